// Round 5
// baseline (348.088 us; speedup 1.0000x reference)
//
#include <hip/hip_runtime.h>

#define BB 512
#define TT 512
#define NN 64
#define NPAIR 256   // grid: block b owns sequences b and b+NPAIR

__device__ __forceinline__ float readlane_f(float v, int lane) {
    return __int_as_float(__builtin_amdgcn_readlane(__float_as_int(v), lane));
}

// R5: two independent recurrences interleaved in ONE wave. R1-R4 showed the
// single chain stalls ~390 cyc/step (issue ~300 of ~690) regardless of
// broadcast mechanism; a second independent chain in the same instruction
// stream fills those holes. Intrinsic readlanes (R4's asm readlane after
// v_exp skipped compiler hazard nops -> absmax 16). E pinned to VGPRs via
// empty-asm so remat/scratch is off the table (verify via VGPR_Count).

#define DOTG(g, Ev) \
    s0 = fmaf(readlane_f(p, 4 * (g) + 0), Ev.x, s0); \
    s1 = fmaf(readlane_f(p, 4 * (g) + 1), Ev.y, s1); \
    s2 = fmaf(readlane_f(p, 4 * (g) + 2), Ev.z, s2); \
    s3 = fmaf(readlane_f(p, 4 * (g) + 3), Ev.w, s3);

#define DOT64(p, sres) { \
    float s0 = readlane_f(p, 0) * E0.x; \
    float s1 = readlane_f(p, 1) * E0.y; \
    float s2 = readlane_f(p, 2) * E0.z; \
    float s3 = readlane_f(p, 3) * E0.w; \
    DOTG(1, E1)   DOTG(2, E2)   DOTG(3, E3) \
    DOTG(4, E4)   DOTG(5, E5)   DOTG(6, E6)   DOTG(7, E7) \
    DOTG(8, E8)   DOTG(9, E9)   DOTG(10, E10) DOTG(11, E11) \
    DOTG(12, E12) DOTG(13, E13) DOTG(14, E14) DOTG(15, E15) \
    sres = (s0 + s1) + (s2 + s3); \
}

// one recurrence step: stale-max shift (exact identity, R3 absmax 0.0)
#define STEP1(av, mv, EMv, tc_, lastv) { \
    const float mu = mv; \
    const float p  = __expf(av - mu); \
    mv = readlane_f(av, 0);   /* shift for NEXT step, off the chain */ \
    float s; \
    DOT64(p, s) \
    if ((tc_) <= lastv) av = ((EMv) + mu) + __logf(s); \
}

// double step: seq0 then seq1 as straight-line code; compiler interleaves.
#define DSTEP(r, EA, EB) \
    STEP1(alpha0, m0, EA, t0 + (r), last0) \
    STEP1(alpha1, m1, EB, t0 + (r), last1)

__global__ __launch_bounds__(64, 1) void crf_kernel(
    const float* __restrict__ inputs,   // B*T*N fp32
    const float* __restrict__ trans,    // N*N fp32
    const int*   __restrict__ tags,     // B*T
    const int*   __restrict__ lens,     // B
    float*       __restrict__ out)      // [0,512) ll, [512,4608) trans copy
{
    const int b = blockIdx.x;
    const int j = threadIdx.x;          // 0..63

    // pass-through output: transition_params (4096 floats over first 64 blocks)
    if (b < 64) out[BB + b * 64 + j] = trans[b * 64 + j];

    const int L0 = lens[b];
    const int L1 = lens[b + NPAIR];
    const int last0 = (L0 - 1) > 0 ? (L0 - 1) : 0;
    const int last1 = (L1 - 1) > 0 ? (L1 - 1) : 0;
    const int lastmax = last0 > last1 ? last0 : last1;

    const float* inb0 = inputs + (size_t)b * TT * NN;
    const float* inb1 = inputs + (size_t)(b + NPAIR) * TT * NN;
    const int*   tagb0 = tags + (size_t)b * TT;
    const int*   tagb1 = tags + (size_t)(b + NPAIR) * TT;

    // ---- sequence scores for both sequences (prologue, off-chain) ----
    float sc0 = 0.f, sc1 = 0.f;
    #pragma unroll
    for (int k = 0; k < 8; ++k) {
        const int t = k * 64 + j;
        const int tg0 = tagb0[t];
        const int tg1 = tagb1[t];
        if (t < L0) sc0 += inb0[t * NN + tg0];
        if (t + 1 < L0) sc0 += trans[tg0 * NN + tagb0[t + 1]];  // L<=511 safe
        if (t < L1) sc1 += inb1[t * NN + tg1];
        if (t + 1 < L1) sc1 += trans[tg1 * NN + tagb1[t + 1]];
    }
    #pragma unroll
    for (int x = 32; x >= 1; x >>= 1) sc0 += __shfl_xor(sc0, x, 64);
    #pragma unroll
    for (int x = 32; x >= 1; x >>= 1) sc1 += __shfl_xor(sc1, x, 64);

    // ---- E column j in named VGPRs, pinned via empty asm (anti-remat) ----
    float4 E0, E1, E2, E3, E4, E5, E6, E7, E8, E9, E10, E11, E12, E13, E14, E15;
#define LDE(Ev, g) \
    Ev.x = __expf(trans[(4 * (g) + 0) * NN + j]); \
    Ev.y = __expf(trans[(4 * (g) + 1) * NN + j]); \
    Ev.z = __expf(trans[(4 * (g) + 2) * NN + j]); \
    Ev.w = __expf(trans[(4 * (g) + 3) * NN + j]);
    LDE(E0, 0)   LDE(E1, 1)   LDE(E2, 2)   LDE(E3, 3)
    LDE(E4, 4)   LDE(E5, 5)   LDE(E6, 6)   LDE(E7, 7)
    LDE(E8, 8)   LDE(E9, 9)   LDE(E10, 10) LDE(E11, 11)
    LDE(E12, 12) LDE(E13, 13) LDE(E14, 14) LDE(E15, 15)
#undef LDE
#define PIN4(Ev) asm volatile("" : "+v"(Ev.x), "+v"(Ev.y), "+v"(Ev.z), "+v"(Ev.w));
    PIN4(E0)  PIN4(E1)  PIN4(E2)  PIN4(E3)
    PIN4(E4)  PIN4(E5)  PIN4(E6)  PIN4(E7)
    PIN4(E8)  PIN4(E9)  PIN4(E10) PIN4(E11)
    PIN4(E12) PIN4(E13) PIN4(E14) PIN4(E15)
#undef PIN4

    float alpha0 = inb0[j];                 // t = 0
    float alpha1 = inb1[j];
    float m0 = readlane_f(alpha0, 0);       // exact shift for first step
    float m1 = readlane_f(alpha1, 0);

    // emit prefetch: 4-step half-chunks, double-buffered, per sequence.
    float4 s0A, s1A, s0B, s1B;

#define LD1(vec, comp, tt, inbp, lastv) { \
    const int tc_ = (tt) <= lastv ? (tt) : lastv; \
    vec.comp = inbp[tc_ * NN + j]; }
#define LOADC4(vec, base, inbp, lastv) \
    LD1(vec, x, (base) + 0, inbp, lastv) \
    LD1(vec, y, (base) + 1, inbp, lastv) \
    LD1(vec, z, (base) + 2, inbp, lastv) \
    LD1(vec, w, (base) + 3, inbp, lastv)

    LOADC4(s0A, 1, inb0, last0)
    LOADC4(s1A, 1, inb1, last1)

    for (int t0 = 1; t0 <= lastmax; t0 += 8) {
        LOADC4(s0B, t0 + 4, inb0, last0)
        LOADC4(s1B, t0 + 4, inb1, last1)
        DSTEP(0, s0A.x, s1A.x)
        DSTEP(1, s0A.y, s1A.y)
        DSTEP(2, s0A.z, s1A.z)
        DSTEP(3, s0A.w, s1A.w)
        LOADC4(s0A, t0 + 8, inb0, last0)
        LOADC4(s1A, t0 + 8, inb1, last1)
        DSTEP(4, s0B.x, s1B.x)
        DSTEP(5, s0B.y, s1B.y)
        DSTEP(6, s0B.z, s1B.z)
        DSTEP(7, s0B.w, s1B.w)
    }
#undef LOADC4
#undef LD1

    // ---- log_norm + outputs for both sequences ----
    {
        float mm = alpha0;
        #pragma unroll
        for (int x = 32; x >= 1; x >>= 1) mm = fmaxf(mm, __shfl_xor(mm, x, 64));
        float e = __expf(alpha0 - mm);
        #pragma unroll
        for (int x = 32; x >= 1; x >>= 1) e += __shfl_xor(e, x, 64);
        if (j == 0) out[b] = sc0 - (mm + __logf(e));
    }
    {
        float mm = alpha1;
        #pragma unroll
        for (int x = 32; x >= 1; x >>= 1) mm = fmaxf(mm, __shfl_xor(mm, x, 64));
        float e = __expf(alpha1 - mm);
        #pragma unroll
        for (int x = 32; x >= 1; x >>= 1) e += __shfl_xor(e, x, 64);
        if (j == 0) out[b + NPAIR] = sc1 - (mm + __logf(e));
    }
}

extern "C" void kernel_launch(void* const* d_in, const int* in_sizes, int n_in,
                              void* d_out, int out_size, void* d_ws, size_t ws_size,
                              hipStream_t stream) {
    const float* inputs = (const float*)d_in[0];
    const float* trans  = (const float*)d_in[1];
    const int*   tags   = (const int*)d_in[2];
    const int*   lens   = (const int*)d_in[3];
    float*       out    = (float*)d_out;

    crf_kernel<<<dim3(NPAIR), dim3(64), 0, stream>>>(inputs, trans, tags, lens, out);
}

// Round 6
// 216.931 us; speedup vs baseline: 1.6046x; 1.6046x over previous
//
#include <hip/hip_runtime.h>

#define BB 512
#define TT 512
#define NN 64

__device__ __forceinline__ float readlane_f(float v, int lane) {
    return __int_as_float(__builtin_amdgcn_readlane(__float_as_int(v), lane));
}

// R6 theory (from R1-R5 evidence):
//  (a) E-REMAT: trans loads are invariant+rematerializable; allocator redoes
//      load+v_exp per use instead of keeping 64 live floats (VGPR_Count was
//      56-68 in EVERY variant -- E never resident). Fix: re-pin E via asm
//      volatile INSIDE the loop each iteration; remat would then have to
//      recompute before every pin, so the allocator must keep VGPRs.
//  (b) SGPR HAZARD: readlane,fma pairs pay VALU-writes-SGPR->VALU-reads-SGPR
//      wait states every pair. Fix: 16 intrinsic readlanes -> sched_barrier(0)
//      -> 16 fmas (hazard distance 16; compiler still inserts required waits,
//      unlike R4's raw-asm race that gave absmax=16).
// Verification: VGPR_Count must JUMP (~130+) if (a) is real; dur should drop
// toward the ~300 cyc/step issue floor if (a)+(b) cover the 690-274 gap.

// one 16-wide group: batched broadcasts, then batched fmas.
#define GRP(G, Ea, Eb, Ec, Ed) { \
    const float r0  = readlane_f(p, (G) * 16 + 0); \
    const float r1  = readlane_f(p, (G) * 16 + 1); \
    const float r2  = readlane_f(p, (G) * 16 + 2); \
    const float r3  = readlane_f(p, (G) * 16 + 3); \
    const float r4  = readlane_f(p, (G) * 16 + 4); \
    const float r5  = readlane_f(p, (G) * 16 + 5); \
    const float r6  = readlane_f(p, (G) * 16 + 6); \
    const float r7  = readlane_f(p, (G) * 16 + 7); \
    const float r8  = readlane_f(p, (G) * 16 + 8); \
    const float r9  = readlane_f(p, (G) * 16 + 9); \
    const float r10 = readlane_f(p, (G) * 16 + 10); \
    const float r11 = readlane_f(p, (G) * 16 + 11); \
    const float r12 = readlane_f(p, (G) * 16 + 12); \
    const float r13 = readlane_f(p, (G) * 16 + 13); \
    const float r14 = readlane_f(p, (G) * 16 + 14); \
    const float r15 = readlane_f(p, (G) * 16 + 15); \
    __builtin_amdgcn_sched_barrier(0); \
    s0 = fmaf(r0,  Ea.x, s0); s1 = fmaf(r1,  Ea.y, s1); \
    s2 = fmaf(r2,  Ea.z, s2); s3 = fmaf(r3,  Ea.w, s3); \
    s0 = fmaf(r4,  Eb.x, s0); s1 = fmaf(r5,  Eb.y, s1); \
    s2 = fmaf(r6,  Eb.z, s2); s3 = fmaf(r7,  Eb.w, s3); \
    s0 = fmaf(r8,  Ec.x, s0); s1 = fmaf(r9,  Ec.y, s1); \
    s2 = fmaf(r10, Ec.z, s2); s3 = fmaf(r11, Ec.w, s3); \
    s0 = fmaf(r12, Ed.x, s0); s1 = fmaf(r13, Ed.y, s1); \
    s2 = fmaf(r14, Ed.z, s2); s3 = fmaf(r15, Ed.w, s3); \
    __builtin_amdgcn_sched_barrier(0); \
}

#define STEP(tc_, EM) { \
    const float mu = m_sh; \
    const float p  = __expf(alpha - mu); \
    m_sh = readlane_f(alpha, 0);  /* stale shift for NEXT step, off chain */ \
    float s0 = 0.f, s1 = 0.f, s2 = 0.f, s3 = 0.f; \
    GRP(0, E0,  E1,  E2,  E3) \
    GRP(1, E4,  E5,  E6,  E7) \
    GRP(2, E8,  E9,  E10, E11) \
    GRP(3, E12, E13, E14, E15) \
    const float s = (s0 + s1) + (s2 + s3); \
    if ((tc_) <= last) alpha = ((EM) + mu) + __logf(s); \
}

__global__ __launch_bounds__(64, 1) void crf_kernel(
    const float* __restrict__ inputs,   // B*T*N fp32
    const float* __restrict__ trans,    // N*N fp32
    const int*   __restrict__ tags,     // B*T
    const int*   __restrict__ lens,     // B
    float*       __restrict__ out)      // [0,512) ll, [512,4608) trans copy
{
    const int b = blockIdx.x;
    const int j = threadIdx.x;          // 0..63

    // pass-through output: transition_params (4096 floats over first 64 blocks)
    if (b < 64) out[BB + b * 64 + j] = trans[b * 64 + j];

    const int L    = lens[b];
    const int last = (L - 1) > 0 ? (L - 1) : 0;

    const float* inb  = inputs + (size_t)b * TT * NN;
    const int*   tagb = tags + (size_t)b * TT;

    // ---- sequence score: unary (t < L) + binary (t+1 < L), 64 lanes x 8 ----
    float sc = 0.f;
    #pragma unroll
    for (int k = 0; k < 8; ++k) {
        const int t  = k * 64 + j;
        const int tg = tagb[t];
        if (t < L) sc += inb[t * NN + tg];
        if (t + 1 < L) sc += trans[tg * NN + tagb[t + 1]];   // L<=511 => safe
    }
    #pragma unroll
    for (int x = 32; x >= 1; x >>= 1) sc += __shfl_xor(sc, x, 64);

    // ---- E column j: E[i][j] = exp(trans[i][j]), 64 named floats ----
    float4 E0, E1, E2, E3, E4, E5, E6, E7, E8, E9, E10, E11, E12, E13, E14, E15;
#define LDE(Ev, g) \
    Ev.x = __expf(trans[(4 * (g) + 0) * NN + j]); \
    Ev.y = __expf(trans[(4 * (g) + 1) * NN + j]); \
    Ev.z = __expf(trans[(4 * (g) + 2) * NN + j]); \
    Ev.w = __expf(trans[(4 * (g) + 3) * NN + j]);
    LDE(E0, 0)   LDE(E1, 1)   LDE(E2, 2)   LDE(E3, 3)
    LDE(E4, 4)   LDE(E5, 5)   LDE(E6, 6)   LDE(E7, 7)
    LDE(E8, 8)   LDE(E9, 9)   LDE(E10, 10) LDE(E11, 11)
    LDE(E12, 12) LDE(E13, 13) LDE(E14, 14) LDE(E15, 15)
#undef LDE

#define PIN4(Ev) asm volatile("" : "+v"(Ev.x), "+v"(Ev.y), "+v"(Ev.z), "+v"(Ev.w));
#define PIN_ALL \
    PIN4(E0)  PIN4(E1)  PIN4(E2)  PIN4(E3) \
    PIN4(E4)  PIN4(E5)  PIN4(E6)  PIN4(E7) \
    PIN4(E8)  PIN4(E9)  PIN4(E10) PIN4(E11) \
    PIN4(E12) PIN4(E13) PIN4(E14) PIN4(E15)

    float alpha = inb[j];                    // t = 0
    float m_sh  = readlane_f(alpha, 0);      // exact shift for first step

    // emit prefetch: 8-step halves, double-buffered (body ~14KB, I$-safe).
    float4 fA0, fA1, fB0, fB1;

#define LD(vec, comp, tt) { const int tc_ = (tt) <= last ? (tt) : last; \
                            vec.comp = inb[tc_ * NN + j]; }
#define LOAD8(v0, v1, base) \
    LD(v0, x, (base) + 0) LD(v0, y, (base) + 1) LD(v0, z, (base) + 2) LD(v0, w, (base) + 3) \
    LD(v1, x, (base) + 4) LD(v1, y, (base) + 5) LD(v1, z, (base) + 6) LD(v1, w, (base) + 7)

    LOAD8(fA0, fA1, 1)

    for (int t0 = 1; t0 <= last; t0 += 16) {
        PIN_ALL   // per-iteration pin: forces E to stay register-resident
        LOAD8(fB0, fB1, t0 + 8)
        STEP(t0 + 0, fA0.x) STEP(t0 + 1, fA0.y) STEP(t0 + 2, fA0.z) STEP(t0 + 3, fA0.w)
        STEP(t0 + 4, fA1.x) STEP(t0 + 5, fA1.y) STEP(t0 + 6, fA1.z) STEP(t0 + 7, fA1.w)
        LOAD8(fA0, fA1, t0 + 16)
        STEP(t0 + 8,  fB0.x) STEP(t0 + 9,  fB0.y) STEP(t0 + 10, fB0.z) STEP(t0 + 11, fB0.w)
        STEP(t0 + 12, fB1.x) STEP(t0 + 13, fB1.y) STEP(t0 + 14, fB1.z) STEP(t0 + 15, fB1.w)
    }
#undef LOAD8
#undef LD
#undef PIN_ALL
#undef PIN4

    // ---- log_norm = logsumexp_j(alpha) ----
    float mm = alpha;
    #pragma unroll
    for (int x = 32; x >= 1; x >>= 1) mm = fmaxf(mm, __shfl_xor(mm, x, 64));
    float e = __expf(alpha - mm);
    #pragma unroll
    for (int x = 32; x >= 1; x >>= 1) e += __shfl_xor(e, x, 64);
    if (j == 0) out[b] = sc - (mm + __logf(e));
}

extern "C" void kernel_launch(void* const* d_in, const int* in_sizes, int n_in,
                              void* d_out, int out_size, void* d_ws, size_t ws_size,
                              hipStream_t stream) {
    const float* inputs = (const float*)d_in[0];
    const float* trans  = (const float*)d_in[1];
    const int*   tags   = (const int*)d_in[2];
    const int*   lens   = (const int*)d_in[3];
    float*       out    = (float*)d_out;

    crf_kernel<<<dim3(BB), dim3(64), 0, stream>>>(inputs, trans, tags, lens, out);
}